// Round 1
// baseline (758.707 us; speedup 1.0000x reference)
//
#include <hip/hip_runtime.h>

#define NMAT 2048
#define KATTR 64
#define CAP 128
#define NITER 10

// --------------------------------------------------------------------------
// Build padded adjacency (ELL) lists for pattern(A). B = (A*1/A^2)*A == (A!=0).
// idx  : row-major ELL  [row][slot]  (u16 col indices)
// idxT : slot-major ELL [slot][row]  (for lane-parallel column gathers)
// A is symmetric by construction in setup_inputs (max(A, A^T)), so the row
// pattern also serves as the column pattern (B^T == B).
// --------------------------------------------------------------------------
__global__ __launch_bounds__(256) void k_build(
    const float* __restrict__ A, unsigned short* __restrict__ idx,
    unsigned short* __restrict__ idxT, int* __restrict__ cnt) {
  __shared__ int lcnt;
  int r = blockIdx.x;
  if (threadIdx.x == 0) lcnt = 0;
  __syncthreads();
  const float* row = A + (size_t)r * NMAT;
  for (int c = threadIdx.x; c < NMAT; c += 256) {
    if (row[c] != 0.0f) {
      int p = atomicAdd(&lcnt, 1);
      if (p < CAP) {
        idx[r * CAP + p] = (unsigned short)c;
        if (idxT) idxT[(size_t)p * NMAT + r] = (unsigned short)c;
      }
    }
  }
  __syncthreads();
  if (threadIdx.x == 0) cnt[r] = lcnt < CAP ? lcnt : CAP;
}

// ------------------- row L2-normalize (one wave per row) -------------------
__global__ __launch_bounds__(256) void k_norm(const float* __restrict__ Nin,
                                              float* __restrict__ Nout) {
  int row = blockIdx.x * 4 + (threadIdx.x >> 6);
  int lane = threadIdx.x & 63;
  float v = Nin[(size_t)row * KATTR + lane];
  float ss = v * v;
#pragma unroll
  for (int o = 32; o > 0; o >>= 1) ss += __shfl_xor(ss, o);
  float nrm = sqrtf(ss);
  Nout[(size_t)row * KATTR + lane] = (nrm > 0.f) ? v / nrm : 0.f;
}

// ------------------- C = B @ Nn : gather-sum of attribute rows -------------
__global__ void k_gatherN(const unsigned short* __restrict__ idx,
                          const int* __restrict__ cnt,
                          const float* __restrict__ Nn,
                          float* __restrict__ C) {
  int i = blockIdx.x;
  int lane = threadIdx.x;  // blockDim = 64
  int nn = cnt[i];
  const unsigned short* ip = idx + i * CAP;
  float acc = 0.f;
  for (int t = 0; t < nn; ++t) {
    int k = ip[t];
    acc += Nn[(size_t)k * KATTR + lane];
  }
  C[(size_t)i * KATTR + lane] = acc;
}

// ------------------- Ht = H^T (tiled transpose) ----------------------------
__global__ __launch_bounds__(256) void k_transpose(const float* __restrict__ H,
                                                   float* __restrict__ Ht) {
  __shared__ float tile[64][65];
  int j0 = blockIdx.x * 64;  // H row block
  int i0 = blockIdx.y * 64;  // H col block
  int c = threadIdx.x & 63;
  int r0 = threadIdx.x >> 6;
  for (int r = r0; r < 64; r += 4)
    tile[r][c] = H[(size_t)(j0 + r) * NMAT + i0 + c];
  __syncthreads();
  for (int r = r0; r < 64; r += 4)
    Ht[(size_t)(i0 + r) * NMAT + j0 + c] = tile[c][r];
}

// --------------------------------------------------------------------------
// q[i,j] = Nm>0&dm>0 ? Nm*rsqrt(Nm*dm) : 0 with Nm = N1n@N2n^T, dm = C1@C2^T.
// Also writes M0 = q * Ht (the first iteration's q*s with s0 = h = H^T).
// 64x64 tile, two K=64 passes (Nm then dm) through the same LDS buffers.
// --------------------------------------------------------------------------
__global__ __launch_bounds__(256) void k_q(
    const float* __restrict__ N1n, const float* __restrict__ C1,
    const float* __restrict__ N2n, const float* __restrict__ C2,
    const float* __restrict__ Ht, float* __restrict__ q,
    float* __restrict__ M) {
  __shared__ float sA[64][68];  // [k][i]
  __shared__ float sB[64][68];  // [k][j]
  int i0 = blockIdx.y * 64, j0 = blockIdx.x * 64;
  int c = threadIdx.x & 63, r0 = threadIdx.x >> 6;
  int tx = threadIdx.x & 15, ty = threadIdx.x >> 4;

  float nmv[4][4] = {};
  float dmv[4][4] = {};

  // pass 1: Nm
  for (int r = r0; r < 64; r += 4) {
    sA[c][r] = N1n[(size_t)(i0 + r) * KATTR + c];
    sB[c][r] = N2n[(size_t)(j0 + r) * KATTR + c];
  }
  __syncthreads();
#pragma unroll 4
  for (int k = 0; k < 64; ++k) {
    float4 a = *(const float4*)&sA[k][ty * 4];
    float4 b = *(const float4*)&sB[k][tx * 4];
    float av[4] = {a.x, a.y, a.z, a.w};
    float bv[4] = {b.x, b.y, b.z, b.w};
#pragma unroll
    for (int ii = 0; ii < 4; ++ii)
#pragma unroll
      for (int jj = 0; jj < 4; ++jj)
        nmv[ii][jj] = fmaf(av[ii], bv[jj], nmv[ii][jj]);
  }
  __syncthreads();
  // pass 2: dm
  for (int r = r0; r < 64; r += 4) {
    sA[c][r] = C1[(size_t)(i0 + r) * KATTR + c];
    sB[c][r] = C2[(size_t)(j0 + r) * KATTR + c];
  }
  __syncthreads();
#pragma unroll 4
  for (int k = 0; k < 64; ++k) {
    float4 a = *(const float4*)&sA[k][ty * 4];
    float4 b = *(const float4*)&sB[k][tx * 4];
    float av[4] = {a.x, a.y, a.z, a.w};
    float bv[4] = {b.x, b.y, b.z, b.w};
#pragma unroll
    for (int ii = 0; ii < 4; ++ii)
#pragma unroll
      for (int jj = 0; jj < 4; ++jj)
        dmv[ii][jj] = fmaf(av[ii], bv[jj], dmv[ii][jj]);
  }

#pragma unroll
  for (int ii = 0; ii < 4; ++ii) {
    int i = i0 + ty * 4 + ii;
    size_t base = (size_t)i * NMAT + j0 + tx * 4;
    float4 hv = *(const float4*)&Ht[base];
    float hvv[4] = {hv.x, hv.y, hv.z, hv.w};
    float qv[4], mv[4];
#pragma unroll
    for (int jj = 0; jj < 4; ++jj) {
      float nmx = nmv[ii][jj];
      float D = nmx * dmv[ii][jj];
      float qq = (D > 0.f) ? nmx * rsqrtf(D) : 0.f;
      qv[jj] = qq;
      mv[jj] = qq * hvv[jj];
    }
    *(float4*)&q[base] = make_float4(qv[0], qv[1], qv[2], qv[3]);
    *(float4*)&M[base] = make_float4(mv[0], mv[1], mv[2], mv[3]);
  }
}

// ------------------- K1: T1 = B1^T @ M (gather-sum of M rows) --------------
__global__ __launch_bounds__(256) void k1_rowgather(
    const unsigned short* __restrict__ idx1, const int* __restrict__ cnt1,
    const float* __restrict__ M, float* __restrict__ T1) {
  int i = blockIdx.x;
  int nn = cnt1[i];
  const unsigned short* ip = idx1 + i * CAP;
  int c0 = threadIdx.x;  // float4 slot
  float4 a0 = {0.f, 0.f, 0.f, 0.f}, a1 = {0.f, 0.f, 0.f, 0.f};
  for (int t = 0; t < nn; ++t) {
    int k = ip[t];
    const float4* mr = (const float4*)(M + (size_t)k * NMAT);
    float4 m0 = mr[c0];
    float4 m1 = mr[c0 + 256];
    a0.x += m0.x; a0.y += m0.y; a0.z += m0.z; a0.w += m0.w;
    a1.x += m1.x; a1.y += m1.y; a1.z += m1.z; a1.w += m1.w;
  }
  float4* tr = (float4*)(T1 + (size_t)i * NMAT);
  tr[c0] = a0;
  tr[c0 + 256] = a1;
}

// --------------------------------------------------------------------------
// K2: S = T1 @ B2^T, fused with s_new = (1-a)*Ht + a*q*S and M = q*s_new.
// 4 rows of T1 interleaved in LDS (rows[k*4+r]) -> one float4 per gather.
// Grid (NMAT/4, 2): block owns rows i0..i0+3 and a 1024-wide j range.
// --------------------------------------------------------------------------
__global__ __launch_bounds__(256) void k2_colgather(
    const unsigned short* __restrict__ idx2T, const int* __restrict__ cnt2,
    const float* __restrict__ T1, const float* __restrict__ q,
    const float* __restrict__ Ht, float* __restrict__ s,
    float* __restrict__ M) {
  __shared__ float rows[NMAT * 4];  // interleaved [k][r], 32 KiB
  const float alpha = 0.82f;
  const float oma = 1.0f - alpha;
  int i0 = blockIdx.x * 4;
  int jb = blockIdx.y * 1024;
#pragma unroll
  for (int r = 0; r < 4; ++r) {
    const float* tr = T1 + (size_t)(i0 + r) * NMAT;
    for (int e = threadIdx.x; e < NMAT; e += 256) rows[e * 4 + r] = tr[e];
  }
  __syncthreads();
#pragma unroll
  for (int jj = 0; jj < 4; ++jj) {
    int j = jb + jj * 256 + threadIdx.x;
    int nn = cnt2[j];
    const unsigned short* ip = idx2T + j;
    float4 acc = {0.f, 0.f, 0.f, 0.f};
    for (int t = 0; t < nn; ++t) {
      int k = ip[(size_t)t * NMAT];
      float4 v = *(const float4*)&rows[k * 4];
      acc.x += v.x; acc.y += v.y; acc.z += v.z; acc.w += v.w;
    }
    float sa[4] = {acc.x, acc.y, acc.z, acc.w};
#pragma unroll
    for (int r = 0; r < 4; ++r) {
      size_t off = (size_t)(i0 + r) * NMAT + j;
      float qv = q[off];
      float sv = oma * Ht[off] + alpha * qv * sa[r];
      s[off] = sv;
      M[off] = qv * sv;
    }
  }
}

extern "C" void kernel_launch(void* const* d_in, const int* in_sizes, int n_in,
                              void* d_out, int out_size, void* d_ws,
                              size_t ws_size, hipStream_t stream) {
  const float* A1 = (const float*)d_in[0];
  const float* A2 = (const float*)d_in[1];
  const float* N1 = (const float*)d_in[2];
  const float* N2 = (const float*)d_in[3];
  const float* H = (const float*)d_in[4];
  float* s_out = (float*)d_out;

  char* p = (char*)d_ws;
  auto take = [&](size_t bytes) {
    char* r = p;
    p += (bytes + 255) & ~(size_t)255;
    return r;
  };
  unsigned short* idx1 = (unsigned short*)take((size_t)NMAT * CAP * 2);
  unsigned short* idx2 = (unsigned short*)take((size_t)NMAT * CAP * 2);
  unsigned short* idx2T = (unsigned short*)take((size_t)CAP * NMAT * 2);
  int* cnt1 = (int*)take((size_t)NMAT * 4);
  int* cnt2 = (int*)take((size_t)NMAT * 4);
  float* N1n = (float*)take((size_t)NMAT * KATTR * 4);
  float* N2n = (float*)take((size_t)NMAT * KATTR * 4);
  float* C1 = (float*)take((size_t)NMAT * KATTR * 4);
  float* C2 = (float*)take((size_t)NMAT * KATTR * 4);
  float* Ht = (float*)take((size_t)NMAT * NMAT * 4);
  float* q = (float*)take((size_t)NMAT * NMAT * 4);
  float* M = (float*)take((size_t)NMAT * NMAT * 4);
  float* T1 = (float*)take((size_t)NMAT * NMAT * 4);
  if ((size_t)(p - (char*)d_ws) > ws_size) return;  // ws too small -> fail loud

  k_build<<<NMAT, 256, 0, stream>>>(A1, idx1, (unsigned short*)nullptr, cnt1);
  k_build<<<NMAT, 256, 0, stream>>>(A2, idx2, idx2T, cnt2);
  k_norm<<<NMAT / 4, 256, 0, stream>>>(N1, N1n);
  k_norm<<<NMAT / 4, 256, 0, stream>>>(N2, N2n);
  k_gatherN<<<NMAT, 64, 0, stream>>>(idx1, cnt1, N1n, C1);
  k_gatherN<<<NMAT, 64, 0, stream>>>(idx2, cnt2, N2n, C2);
  k_transpose<<<dim3(32, 32), 256, 0, stream>>>(H, Ht);
  k_q<<<dim3(32, 32), 256, 0, stream>>>(N1n, C1, N2n, C2, Ht, q, M);
  for (int it = 0; it < NITER; ++it) {
    k1_rowgather<<<NMAT, 256, 0, stream>>>(idx1, cnt1, M, T1);
    k2_colgather<<<dim3(NMAT / 4, 2), 256, 0, stream>>>(idx2T, cnt2, T1, q,
                                                        Ht, s_out, M);
  }
}

// Round 2
// 638.204 us; speedup vs baseline: 1.1888x; 1.1888x over previous
//
#include <hip/hip_runtime.h>

#define NMAT 2048
#define KATTR 64
#define CAP 128
#define NITER 10
#define NCHUNK 8
#define CW (NMAT / NCHUNK)  // 256 columns -> 2 MB slice of M, fits one XCD L2

// --------------------------------------------------------------------------
// Build padded adjacency (ELL) lists for pattern(A). B = (A*1/A^2)*A == (A!=0).
// A is symmetric (max(A,A^T)) so row pattern == column pattern (B^T == B).
// --------------------------------------------------------------------------
__global__ __launch_bounds__(256) void k_build(
    const float* __restrict__ A, unsigned short* __restrict__ idx,
    unsigned short* __restrict__ idxT, int* __restrict__ cnt) {
  __shared__ int lcnt;
  int r = blockIdx.x;
  if (threadIdx.x == 0) lcnt = 0;
  __syncthreads();
  const float* row = A + (size_t)r * NMAT;
  for (int c = threadIdx.x; c < NMAT; c += 256) {
    if (row[c] != 0.0f) {
      int p = atomicAdd(&lcnt, 1);
      if (p < CAP) {
        idx[r * CAP + p] = (unsigned short)c;
        if (idxT) idxT[(size_t)p * NMAT + r] = (unsigned short)c;
      }
    }
  }
  __syncthreads();
  if (threadIdx.x == 0) cnt[r] = lcnt < CAP ? lcnt : CAP;
}

// ------------------- row L2-normalize (one wave per row) -------------------
__global__ __launch_bounds__(256) void k_norm(const float* __restrict__ Nin,
                                              float* __restrict__ Nout) {
  int row = blockIdx.x * 4 + (threadIdx.x >> 6);
  int lane = threadIdx.x & 63;
  float v = Nin[(size_t)row * KATTR + lane];
  float ss = v * v;
#pragma unroll
  for (int o = 32; o > 0; o >>= 1) ss += __shfl_xor(ss, o);
  float nrm = sqrtf(ss);
  Nout[(size_t)row * KATTR + lane] = (nrm > 0.f) ? v / nrm : 0.f;
}

// ------------------- C = B @ Nn : gather-sum of attribute rows -------------
__global__ void k_gatherN(const unsigned short* __restrict__ idx,
                          const int* __restrict__ cnt,
                          const float* __restrict__ Nn,
                          float* __restrict__ C) {
  int i = blockIdx.x;
  int lane = threadIdx.x;  // blockDim = 64
  int nn = cnt[i];
  const unsigned short* ip = idx + i * CAP;
  float acc = 0.f;
  for (int t = 0; t < nn; ++t) {
    int k = ip[t];
    acc += Nn[(size_t)k * KATTR + lane];
  }
  C[(size_t)i * KATTR + lane] = acc;
}

// ------------------- Ht = H^T (tiled transpose) ----------------------------
__global__ __launch_bounds__(256) void k_transpose(const float* __restrict__ H,
                                                   float* __restrict__ Ht) {
  __shared__ float tile[64][65];
  int j0 = blockIdx.x * 64;
  int i0 = blockIdx.y * 64;
  int c = threadIdx.x & 63;
  int r0 = threadIdx.x >> 6;
  for (int r = r0; r < 64; r += 4)
    tile[r][c] = H[(size_t)(j0 + r) * NMAT + i0 + c];
  __syncthreads();
  for (int r = r0; r < 64; r += 4)
    Ht[(size_t)(i0 + r) * NMAT + j0 + c] = tile[c][r];
}

// --------------------------------------------------------------------------
// q[i,j] = Nm>0&dm>0 ? Nm*rsqrt(Nm*dm) : 0; also M0 = q * Ht (iter-0 q*s).
// --------------------------------------------------------------------------
__global__ __launch_bounds__(256) void k_q(
    const float* __restrict__ N1n, const float* __restrict__ C1,
    const float* __restrict__ N2n, const float* __restrict__ C2,
    const float* __restrict__ Ht, float* __restrict__ q,
    float* __restrict__ M) {
  __shared__ float sA[64][68];
  __shared__ float sB[64][68];
  int i0 = blockIdx.y * 64, j0 = blockIdx.x * 64;
  int c = threadIdx.x & 63, r0 = threadIdx.x >> 6;
  int tx = threadIdx.x & 15, ty = threadIdx.x >> 4;

  float nmv[4][4] = {};
  float dmv[4][4] = {};

  for (int r = r0; r < 64; r += 4) {
    sA[c][r] = N1n[(size_t)(i0 + r) * KATTR + c];
    sB[c][r] = N2n[(size_t)(j0 + r) * KATTR + c];
  }
  __syncthreads();
#pragma unroll 4
  for (int k = 0; k < 64; ++k) {
    float4 a = *(const float4*)&sA[k][ty * 4];
    float4 b = *(const float4*)&sB[k][tx * 4];
    float av[4] = {a.x, a.y, a.z, a.w};
    float bv[4] = {b.x, b.y, b.z, b.w};
#pragma unroll
    for (int ii = 0; ii < 4; ++ii)
#pragma unroll
      for (int jj = 0; jj < 4; ++jj)
        nmv[ii][jj] = fmaf(av[ii], bv[jj], nmv[ii][jj]);
  }
  __syncthreads();
  for (int r = r0; r < 64; r += 4) {
    sA[c][r] = C1[(size_t)(i0 + r) * KATTR + c];
    sB[c][r] = C2[(size_t)(j0 + r) * KATTR + c];
  }
  __syncthreads();
#pragma unroll 4
  for (int k = 0; k < 64; ++k) {
    float4 a = *(const float4*)&sA[k][ty * 4];
    float4 b = *(const float4*)&sB[k][tx * 4];
    float av[4] = {a.x, a.y, a.z, a.w};
    float bv[4] = {b.x, b.y, b.z, b.w};
#pragma unroll
    for (int ii = 0; ii < 4; ++ii)
#pragma unroll
      for (int jj = 0; jj < 4; ++jj)
        dmv[ii][jj] = fmaf(av[ii], bv[jj], dmv[ii][jj]);
  }

#pragma unroll
  for (int ii = 0; ii < 4; ++ii) {
    int i = i0 + ty * 4 + ii;
    size_t base = (size_t)i * NMAT + j0 + tx * 4;
    float4 hv = *(const float4*)&Ht[base];
    float hvv[4] = {hv.x, hv.y, hv.z, hv.w};
    float qv[4], mv[4];
#pragma unroll
    for (int jj = 0; jj < 4; ++jj) {
      float nmx = nmv[ii][jj];
      float D = nmx * dmv[ii][jj];
      float qq = (D > 0.f) ? nmx * rsqrtf(D) : 0.f;
      qv[jj] = qq;
      mv[jj] = qq * hvv[jj];
    }
    *(float4*)&q[base] = make_float4(qv[0], qv[1], qv[2], qv[3]);
    *(float4*)&M[base] = make_float4(mv[0], mv[1], mv[2], mv[3]);
  }
}

// --------------------------------------------------------------------------
// K1: T1 = B1 @ M, column-chunked for XCD-L2 residency.
// chunk c = blockIdx % 8 (round-robin XCD heuristic): all blocks on XCD c
// gather only from M[:, c*256 .. c*256+255] (2 MB -> L2-resident slice).
// One wave per output row; 64 lanes x float4 = 256 cols = one chunk width.
// --------------------------------------------------------------------------
__global__ __launch_bounds__(256) void k1_rowgather(
    const unsigned short* __restrict__ idx1, const int* __restrict__ cnt1,
    const float* __restrict__ M, float* __restrict__ T1) {
  int c = blockIdx.x & (NCHUNK - 1);
  int rg = blockIdx.x >> 3;
  int wave = threadIdx.x >> 6;
  int lane = threadIdx.x & 63;
  int i = rg * 4 + wave;
  int nn = cnt1[i];
  const unsigned short* ip = idx1 + i * CAP;
  size_t coff = (size_t)c * CW + (size_t)lane * 4;
  float4 a0 = {0.f, 0.f, 0.f, 0.f}, a1 = {0.f, 0.f, 0.f, 0.f};
  int t = 0;
  for (; t + 2 <= nn; t += 2) {
    unsigned pr = *(const unsigned*)(ip + t);  // ip 4B-aligned, t even
    int k0 = pr & 0xffff;
    int k1v = pr >> 16;
    float4 v0 = *(const float4*)(M + (size_t)k0 * NMAT + coff);
    float4 v1 = *(const float4*)(M + (size_t)k1v * NMAT + coff);
    a0.x += v0.x; a0.y += v0.y; a0.z += v0.z; a0.w += v0.w;
    a1.x += v1.x; a1.y += v1.y; a1.z += v1.z; a1.w += v1.w;
  }
  if (t < nn) {
    int k0 = ip[t];
    float4 v0 = *(const float4*)(M + (size_t)k0 * NMAT + coff);
    a0.x += v0.x; a0.y += v0.y; a0.z += v0.z; a0.w += v0.w;
  }
  a0.x += a1.x; a0.y += a1.y; a0.z += a1.z; a0.w += a1.w;
  *(float4*)(T1 + (size_t)i * NMAT + coff) = a0;
}

// --------------------------------------------------------------------------
// K2: S = T1 @ B2^T fused with s_new = (1-a)*Ht + a*q*S and M = q*s_new.
// Planar LDS rows[4][NMAT]: conflict-free b128 staging, ~free 2-way b32
// gathers. Grid (512): block owns 4 T1 rows x full j width (stages T1 once).
// Intermediate iters write only M; final iter writes only s (d_out).
// --------------------------------------------------------------------------
__global__ __launch_bounds__(256) void k2_colgather(
    const unsigned short* __restrict__ idx2T, const int* __restrict__ cnt2,
    const float* __restrict__ T1, const float* __restrict__ q,
    const float* __restrict__ Ht, float* __restrict__ sout,
    float* __restrict__ M, int last) {
  __shared__ float rows[4][NMAT];  // 32 KiB
  const float alpha = 0.82f;
  const float oma = 1.0f - alpha;
  int i0 = blockIdx.x * 4;
#pragma unroll
  for (int r = 0; r < 4; ++r) {
    const float4* tr = (const float4*)(T1 + (size_t)(i0 + r) * NMAT);
    float4* dst = (float4*)rows[r];
    for (int e = threadIdx.x; e < NMAT / 4; e += 256) dst[e] = tr[e];
  }
  __syncthreads();
#pragma unroll
  for (int jj = 0; jj < 8; ++jj) {
    int j = jj * 256 + threadIdx.x;
    int nn = cnt2[j];
    const unsigned short* ip = idx2T + j;
    float s0 = 0.f, s1 = 0.f, s2 = 0.f, s3 = 0.f;
    float u0 = 0.f, u1 = 0.f, u2 = 0.f, u3 = 0.f;
    int t = 0;
    for (; t + 2 <= nn; t += 2) {
      int ka = ip[(size_t)t * NMAT];
      int kb = ip[(size_t)(t + 1) * NMAT];
      s0 += rows[0][ka]; s1 += rows[1][ka];
      s2 += rows[2][ka]; s3 += rows[3][ka];
      u0 += rows[0][kb]; u1 += rows[1][kb];
      u2 += rows[2][kb]; u3 += rows[3][kb];
    }
    if (t < nn) {
      int ka = ip[(size_t)t * NMAT];
      s0 += rows[0][ka]; s1 += rows[1][ka];
      s2 += rows[2][ka]; s3 += rows[3][ka];
    }
    float sa[4] = {s0 + u0, s1 + u1, s2 + u2, s3 + u3};
#pragma unroll
    for (int r = 0; r < 4; ++r) {
      size_t off = (size_t)(i0 + r) * NMAT + j;
      float qv = q[off];
      float sv = oma * Ht[off] + alpha * qv * sa[r];
      if (last) sout[off] = sv;
      else M[off] = qv * sv;
    }
  }
}

extern "C" void kernel_launch(void* const* d_in, const int* in_sizes, int n_in,
                              void* d_out, int out_size, void* d_ws,
                              size_t ws_size, hipStream_t stream) {
  const float* A1 = (const float*)d_in[0];
  const float* A2 = (const float*)d_in[1];
  const float* N1 = (const float*)d_in[2];
  const float* N2 = (const float*)d_in[3];
  const float* H = (const float*)d_in[4];
  float* s_out = (float*)d_out;

  char* p = (char*)d_ws;
  auto take = [&](size_t bytes) {
    char* r = p;
    p += (bytes + 255) & ~(size_t)255;
    return r;
  };
  unsigned short* idx1 = (unsigned short*)take((size_t)NMAT * CAP * 2);
  unsigned short* idx2 = (unsigned short*)take((size_t)NMAT * CAP * 2);
  unsigned short* idx2T = (unsigned short*)take((size_t)CAP * NMAT * 2);
  int* cnt1 = (int*)take((size_t)NMAT * 4);
  int* cnt2 = (int*)take((size_t)NMAT * 4);
  float* N1n = (float*)take((size_t)NMAT * KATTR * 4);
  float* N2n = (float*)take((size_t)NMAT * KATTR * 4);
  float* C1 = (float*)take((size_t)NMAT * KATTR * 4);
  float* C2 = (float*)take((size_t)NMAT * KATTR * 4);
  float* Ht = (float*)take((size_t)NMAT * NMAT * 4);
  float* q = (float*)take((size_t)NMAT * NMAT * 4);
  float* M = (float*)take((size_t)NMAT * NMAT * 4);
  float* T1 = (float*)take((size_t)NMAT * NMAT * 4);
  if ((size_t)(p - (char*)d_ws) > ws_size) return;

  k_build<<<NMAT, 256, 0, stream>>>(A1, idx1, (unsigned short*)nullptr, cnt1);
  k_build<<<NMAT, 256, 0, stream>>>(A2, idx2, idx2T, cnt2);
  k_norm<<<NMAT / 4, 256, 0, stream>>>(N1, N1n);
  k_norm<<<NMAT / 4, 256, 0, stream>>>(N2, N2n);
  k_gatherN<<<NMAT, 64, 0, stream>>>(idx1, cnt1, N1n, C1);
  k_gatherN<<<NMAT, 64, 0, stream>>>(idx2, cnt2, N2n, C2);
  k_transpose<<<dim3(32, 32), 256, 0, stream>>>(H, Ht);
  k_q<<<dim3(32, 32), 256, 0, stream>>>(N1n, C1, N2n, C2, Ht, q, M);
  for (int it = 0; it < NITER; ++it) {
    k1_rowgather<<<NCHUNK * (NMAT / 4), 256, 0, stream>>>(idx1, cnt1, M, T1);
    k2_colgather<<<NMAT / 4, 256, 0, stream>>>(idx2T, cnt2, T1, q, Ht, s_out,
                                               M, it == NITER - 1 ? 1 : 0);
  }
}